// Round 1
// baseline (206.449 us; speedup 1.0000x reference)
//
#include <hip/hip_runtime.h>
#include <math.h>

#define N0 3190
#define NT 32768
#define E0 51040
#define CH 512   // x0 rows per LDS chunk

// ws layout (floats):
// [0,N0)        n0
// [N0,2N0)      rn0 = 1/n0
// [2N0,12N0)    agg (N0*10)
// [12N0,13N0)   cnt
// [13N0,28N0)   o1_0 (N0*15)

__global__ void prep_x0(const float* __restrict__ x0, float* __restrict__ ws) {
    int i = blockIdx.x * 256 + threadIdx.x;
    if (i >= N0) return;
    float s = 0.f;
#pragma unroll
    for (int c = 0; c < 10; ++c) { float v = x0[i * 10 + c]; s = fmaf(v, v, s); }
    float n = sqrtf(s);
    ws[i] = n;
    ws[N0 + i] = 1.0f / n;
#pragma unroll
    for (int c = 0; c < 10; ++c) ws[2 * N0 + i * 10 + c] = 0.f;
    ws[12 * N0 + i] = 0.f;
}

__global__ void sage1_scatter(const float* __restrict__ x0, const int* __restrict__ e0,
                              float* __restrict__ ws) {
    int e = blockIdx.x * 256 + threadIdx.x;
    if (e >= E0) return;
    int s = e0[e];
    int d = e0[E0 + e];
    float* agg = ws + 2 * N0;
#pragma unroll
    for (int c = 0; c < 10; ++c) atomicAdd(&agg[d * 10 + c], x0[s * 10 + c]);
    atomicAdd(&ws[12 * N0 + d], 1.0f);
}

__global__ void sage1_finish(const float* __restrict__ x0,
                             const float* __restrict__ c1_wl, const float* __restrict__ c1_bl,
                             const float* __restrict__ c1_wr, float* __restrict__ ws) {
    int i = blockIdx.x * 256 + threadIdx.x;
    if (i >= N0) return;
    const float* agg = ws + 2 * N0 + i * 10;
    float den = fmaxf(ws[12 * N0 + i], 1.0f);
    float m[10], xr[10];
#pragma unroll
    for (int c = 0; c < 10; ++c) { m[c] = agg[c] / den; xr[c] = x0[i * 10 + c]; }
    float* o = ws + 13 * N0 + i * 15;
#pragma unroll
    for (int k = 0; k < 15; ++k) {
        float s = c1_bl[k];
#pragma unroll
        for (int c = 0; c < 10; ++c) s = fmaf(m[c], c1_wl[k * 10 + c], s);
#pragma unroll
        for (int c = 0; c < 10; ++c) s = fmaf(xr[c], c1_wr[k * 10 + c], s);
        o[k] = fmaxf(s, 0.f);
    }
}

#define BETTER(k, j, v, i) ((k) > (v) || ((k) == (v) && (j) < (i)))

__launch_bounds__(256)
__global__ void main_kernel(const float* __restrict__ x, const float* __restrict__ x0,
                            const float* __restrict__ emb_w, const float* __restrict__ fc_w,
                            const float* __restrict__ fc_b, const float* __restrict__ fc2_w,
                            const float* __restrict__ fc2_b,
                            const float* __restrict__ c1_wr, const float* __restrict__ c1_bl,
                            const float* __restrict__ c2_wl, const float* __restrict__ c2_bl,
                            const float* __restrict__ c2_wr,
                            const float* __restrict__ lin_w, const float* __restrict__ lin_b,
                            const float* __restrict__ ws, float* __restrict__ out) {
    __shared__ float s_emb[25], s_fcw[1200], s_fcb[20], s_fc2w[1000], s_fc2b[10];
    __shared__ float s_c1wr[150], s_c1bl[15], s_c2wl[150], s_c2bl[10], s_c2wr[150];
    __shared__ float s_linw[30], s_linb[3];
    __shared__ __align__(16) float s_x0[CH * 12];
    __shared__ float s_rn0[CH];
    __shared__ float s_mv[64 * 24];
    __shared__ int   s_mi[64 * 24];

    const int tid = threadIdx.x;
    for (int i = tid; i < 25;   i += 256) s_emb[i]  = emb_w[i];
    for (int i = tid; i < 1200; i += 256) s_fcw[i]  = fc_w[i];
    for (int i = tid; i < 20;   i += 256) s_fcb[i]  = fc_b[i];
    for (int i = tid; i < 1000; i += 256) s_fc2w[i] = fc2_w[i];
    for (int i = tid; i < 10;   i += 256) s_fc2b[i] = fc2_b[i];
    for (int i = tid; i < 150;  i += 256) s_c1wr[i] = c1_wr[i];
    for (int i = tid; i < 15;   i += 256) s_c1bl[i] = c1_bl[i];
    for (int i = tid; i < 150;  i += 256) s_c2wl[i] = c2_wl[i];
    for (int i = tid; i < 10;   i += 256) s_c2bl[i] = c2_bl[i];
    for (int i = tid; i < 150;  i += 256) s_c2wr[i] = c2_wr[i];
    for (int i = tid; i < 30;   i += 256) s_linw[i] = lin_w[i];
    for (int i = tid; i < 3;    i += 256) s_linb[i] = lin_b[i];
    __syncthreads();

    const int node = blockIdx.x * 64 + (tid >> 2);
    const int q = tid & 3;

    // ---------- encoder (k-quarter per lane) ----------
    float acc[5][5];   // [e][kl], k = 5*q+kl
#pragma unroll
    for (int e = 0; e < 5; ++e)
#pragma unroll
        for (int kl = 0; kl < 5; ++kl) acc[e][kl] = 0.f;

    const float* xp = x + (size_t)node * 5;
    for (int f = 0; f < 60; ++f) {
        float xin[5];
#pragma unroll
        for (int c = 0; c < 5; ++c) xin[c] = xp[(size_t)f * NT * 5 + c];
        float hm[5];
#pragma unroll
        for (int e = 0; e < 5; ++e) {
            float s = 0.f;
#pragma unroll
            for (int c = 0; c < 5; ++c) s = fmaf(xin[c], s_emb[c * 5 + e], s);
            hm[e] = fmaxf(s, 0.f);
        }
#pragma unroll
        for (int kl = 0; kl < 5; ++kl) {
            float w = s_fcw[(5 * q + kl) * 60 + f];
#pragma unroll
            for (int e = 0; e < 5; ++e) acc[e][kl] = fmaf(hm[e], w, acc[e][kl]);
        }
    }

    float hp[10];
#pragma unroll
    for (int u = 0; u < 10; ++u) hp[u] = 0.f;
#pragma unroll
    for (int kl = 0; kl < 5; ++kl) {
        const int k = 5 * q + kl;
#pragma unroll
        for (int e = 0; e < 5; ++e) {
            float z = fmaxf(acc[e][kl] + s_fcb[k], 0.f);
            const int zi = k * 5 + e;
#pragma unroll
            for (int u = 0; u < 10; ++u) hp[u] = fmaf(s_fc2w[u * 100 + zi], z, hp[u]);
        }
    }
#pragma unroll
    for (int u = 0; u < 10; ++u) {
        hp[u] += __shfl_xor(hp[u], 1);
        hp[u] += __shfl_xor(hp[u], 2);
    }
    float h[10];
#pragma unroll
    for (int u = 0; u < 10; ++u) h[u] = fmaxf(hp[u] + s_fc2b[u], 0.f);

    float nh2 = 0.f;
#pragma unroll
    for (int u = 0; u < 10; ++u) nh2 = fmaf(h[u], h[u], nh2);
    const float nh = sqrtf(nh2);

    // SAGE1 at test node: no incoming edge_0 edges -> agg=0
    float o1t[15];
#pragma unroll
    for (int k = 0; k < 15; ++k) {
        float s = s_c1bl[k];
#pragma unroll
        for (int u = 0; u < 10; ++u) s = fmaf(h[u], s_c1wr[k * 10 + u], s);
        o1t[k] = fmaxf(s, 0.f);
    }

    // ---------- cosine top-6 (stable), j strided by quad lane ----------
    float v0 = -INFINITY, v1 = -INFINITY, v2 = -INFINITY, v3 = -INFINITY, v4 = -INFINITY, v5 = -INFINITY;
    int i0 = 0, i1 = 0, i2 = 0, i3 = 0, i4 = 0, i5 = 0;

    for (int c0 = 0; c0 < N0; c0 += CH) {
        const int cn = min(CH, N0 - c0);
        __syncthreads();
        for (int idx = tid; idx < cn * 10; idx += 256) {
            int r = idx / 10;
            int cc = idx - r * 10;
            s_x0[r * 12 + cc] = x0[(size_t)(c0 + r) * 10 + cc];
        }
        for (int idx = tid; idx < cn; idx += 256) s_rn0[idx] = ws[N0 + c0 + idx];
        __syncthreads();
        for (int j = q; j < cn; j += 4) {
            const float* r = &s_x0[j * 12];
            float dot = 0.f;
#pragma unroll
            for (int c = 0; c < 10; ++c) dot = fmaf(h[c], r[c], dot);
            float key = dot * s_rn0[j];
            if (key > v5) {
                int jj = c0 + j;
                if (key > v4) { v5 = v4; i5 = i4;
                    if (key > v3) { v4 = v3; i4 = i3;
                        if (key > v2) { v3 = v2; i3 = i2;
                            if (key > v1) { v2 = v1; i2 = i1;
                                if (key > v0) { v1 = v0; i1 = i0; v0 = key; i0 = jj; }
                                else { v1 = key; i1 = jj; }
                            } else { v2 = key; i2 = jj; }
                        } else { v3 = key; i3 = jj; }
                    } else { v4 = key; i4 = jj; }
                } else { v5 = key; i5 = jj; }
            }
        }
    }

    // ---------- merge 4 lanes' top-6 -> global stable top-6 ----------
    const int nl = tid >> 2;
    {
        int b = nl * 24 + q * 6;
        s_mv[b + 0] = v0; s_mi[b + 0] = i0;
        s_mv[b + 1] = v1; s_mi[b + 1] = i1;
        s_mv[b + 2] = v2; s_mi[b + 2] = i2;
        s_mv[b + 3] = v3; s_mi[b + 3] = i3;
        s_mv[b + 4] = v4; s_mi[b + 4] = i4;
        s_mv[b + 5] = v5; s_mi[b + 5] = i5;
    }
    __syncthreads();

    if (q == 0) {
        float m0 = -INFINITY, m1 = -INFINITY, m2 = -INFINITY, m3 = -INFINITY, m4 = -INFINITY, m5 = -INFINITY;
        int j0 = 0, j1 = 0, j2 = 0, j3 = 0, j4 = 0, j5 = 0;
        for (int s = 0; s < 24; ++s) {
            float kv = s_mv[nl * 24 + s];
            int ki = s_mi[nl * 24 + s];
            if (BETTER(kv, ki, m5, j5)) {
                if (BETTER(kv, ki, m4, j4)) { m5 = m4; j5 = j4;
                    if (BETTER(kv, ki, m3, j3)) { m4 = m3; j4 = j3;
                        if (BETTER(kv, ki, m2, j2)) { m3 = m2; j3 = j2;
                            if (BETTER(kv, ki, m1, j1)) { m2 = m1; j2 = j1;
                                if (BETTER(kv, ki, m0, j0)) { m1 = m0; j1 = j0; m0 = kv; j0 = ki; }
                                else { m1 = kv; j1 = ki; }
                            } else { m2 = kv; j2 = ki; }
                        } else { m3 = kv; j3 = ki; }
                    } else { m4 = kv; j4 = ki; }
                } else { m5 = kv; j5 = ki; }
            }
        }

        // selfmatch: recompute exact a = (dot/nh)/n0 for the top entry
        float dot0 = 0.f;
        const float* xr = x0 + (size_t)j0 * 10;
#pragma unroll
        for (int c = 0; c < 10; ++c) dot0 = fmaf(h[c], xr[c], dot0);
        float a0 = (dot0 / nh) / ws[j0];
        bool selfm = (a0 == 1.0f);
        int n1 = selfm ? j1 : j0;
        int n2 = selfm ? j2 : j1;
        int n3 = selfm ? j3 : j2;
        int n4 = selfm ? j4 : j3;
        int n5 = selfm ? j5 : j4;

        const float* o10 = ws + 13 * N0;
        float mean[15];
#pragma unroll
        for (int k = 0; k < 15; ++k) {
            float s = o10[(size_t)n1 * 15 + k];
            s += o10[(size_t)n2 * 15 + k];
            s += o10[(size_t)n3 * 15 + k];
            s += o10[(size_t)n4 * 15 + k];
            s += o10[(size_t)n5 * 15 + k];
            mean[k] = s / 5.0f;
        }

        float o2[10];
#pragma unroll
        for (int u = 0; u < 10; ++u) {
            float s = s_c2bl[u];
#pragma unroll
            for (int k = 0; k < 15; ++k) s = fmaf(mean[k], s_c2wl[u * 15 + k], s);
#pragma unroll
            for (int k = 0; k < 15; ++k) s = fmaf(o1t[k], s_c2wr[u * 15 + k], s);
            o2[u] = s;
        }

        float l0 = s_linb[0], l1 = s_linb[1], l2 = s_linb[2];
#pragma unroll
        for (int u = 0; u < 10; ++u) {
            l0 = fmaf(o2[u], s_linw[u], l0);
            l1 = fmaf(o2[u], s_linw[10 + u], l1);
            l2 = fmaf(o2[u], s_linw[20 + u], l2);
        }
        float mx = fmaxf(l0, fmaxf(l1, l2));
        float e0 = expf(l0 - mx), e1 = expf(l1 - mx), e2 = expf(l2 - mx);
        float sum = e0 + e1 + e2;
        out[(size_t)node * 3 + 0] = e0 / sum;
        out[(size_t)node * 3 + 1] = e1 / sum;
        out[(size_t)node * 3 + 2] = e2 / sum;
    }
}

extern "C" void kernel_launch(void* const* d_in, const int* in_sizes, int n_in,
                              void* d_out, int out_size, void* d_ws, size_t ws_size,
                              hipStream_t stream) {
    const float* x     = (const float*)d_in[0];
    const float* x0    = (const float*)d_in[1];
    const int*   e0    = (const int*)d_in[2];
    const float* emb_w = (const float*)d_in[3];
    const float* fc_w  = (const float*)d_in[4];
    const float* fc_b  = (const float*)d_in[5];
    const float* fc2_w = (const float*)d_in[6];
    const float* fc2_b = (const float*)d_in[7];
    const float* c1_wl = (const float*)d_in[8];
    const float* c1_bl = (const float*)d_in[9];
    const float* c1_wr = (const float*)d_in[10];
    const float* c2_wl = (const float*)d_in[11];
    const float* c2_bl = (const float*)d_in[12];
    const float* c2_wr = (const float*)d_in[13];
    const float* lin_w = (const float*)d_in[14];
    const float* lin_b = (const float*)d_in[15];
    float* ws  = (float*)d_ws;
    float* out = (float*)d_out;

    prep_x0<<<(N0 + 255) / 256, 256, 0, stream>>>(x0, ws);
    sage1_scatter<<<(E0 + 255) / 256, 256, 0, stream>>>(x0, e0, ws);
    sage1_finish<<<(N0 + 255) / 256, 256, 0, stream>>>(x0, c1_wl, c1_bl, c1_wr, ws);
    main_kernel<<<NT / 64, 256, 0, stream>>>(x, x0, emb_w, fc_w, fc_b, fc2_w, fc2_b,
                                             c1_wr, c1_bl, c2_wl, c2_bl, c2_wr,
                                             lin_w, lin_b, ws, out);
}